// Round 10
// baseline (500.545 us; speedup 1.0000x reference)
//
#include <hip/hip_runtime.h>
#include <math.h>

#define NN 8192
#define FF 256
#define ALPHA 0.2f

typedef __bf16 bf16x8 __attribute__((ext_vector_type(8)));
typedef __bf16 bf16x4 __attribute__((ext_vector_type(4)));
typedef float  f32x4  __attribute__((ext_vector_type(4)));

__device__ __forceinline__ void dma16(const void* g, void* l) {
    __builtin_amdgcn_global_load_lds((const __attribute__((address_space(1))) void*)g,
                                     (__attribute__((address_space(3))) void*)l,
                                     16, 0, 0);
}

#define VMCNT4   asm volatile("s_waitcnt vmcnt(4)" ::: "memory")
#define LGKM0    asm volatile("s_waitcnt lgkmcnt(0)" ::: "memory")
#define BARRIER  asm volatile("s_barrier" ::: "memory")
#define FENCE    asm volatile("" ::: "memory")

// ---------------- K0: WT[hl][n][k] bf16 hi/lo from W[k][n] fp32 -----------
__global__ __launch_bounds__(256) void k0_wt(const float* __restrict__ W,
                                             __bf16* __restrict__ WT) {
    __shared__ float ts[64][65];
    const int t = threadIdx.x;
    const int k0 = blockIdx.x * 64;
    const int n0 = blockIdx.y * 64;
    #pragma unroll
    for (int r = 0; r < 4; ++r) {
        int krow = r * 16 + (t >> 4);
        int nc4 = (t & 15) * 4;
        *(float4*)&ts[krow][nc4] = *(const float4*)&W[(size_t)(k0 + krow) * FF + n0 + nc4];
    }
    __syncthreads();
    const int nloc = t >> 2;
    const int kc = (t & 3) * 16;
    union { bf16x8 v[2]; __bf16 e[16]; } hi, lo;
    #pragma unroll
    for (int u = 0; u < 16; ++u) {
        float x = ts[kc + u][nloc];
        __bf16 h1 = (__bf16)x;
        hi.e[u] = h1;
        lo.e[u] = (__bf16)(x - (float)h1);
    }
    size_t base = (size_t)(n0 + nloc) * FF + k0 + kc;
    *(bf16x8*)&WT[base] = hi.v[0];
    *(bf16x8*)&WT[base + 8] = hi.v[1];
    size_t lbase = (size_t)FF * FF + base;
    *(bf16x8*)&WT[lbase] = lo.v[0];
    *(bf16x8*)&WT[lbase + 8] = lo.v[1];
}

// ---------------- K5: bit-pack adj -> mask (8 MB) -------------------------
__global__ __launch_bounds__(256) void k5_pack(const int* __restrict__ adj,
                                               unsigned int* __restrict__ mask) {
    const int wv = threadIdx.x >> 6, l = threadIdx.x & 63;
    const size_t nwords = (size_t)NN * NN / 64;
    const size_t nw = (size_t)gridDim.x * 4;
    for (size_t w = (size_t)blockIdx.x * 4 + wv; w < nwords; w += nw) {
        int v = adj[w * 64 + l];
        unsigned long long b = __ballot(v > 0);
        if (l == 0) *(unsigned long long*)&mask[w * 2] = b;
    }
}

// ---------------- K1: MFMA h-tile -> hT (hi only, transposed) + src/dst ---
__global__ __launch_bounds__(256) void k1_h(const float* __restrict__ X,
                                            const __bf16* __restrict__ WT,
                                            const float* __restrict__ a,
                                            __bf16* __restrict__ hT,
                                            float* __restrict__ src,
                                            float* __restrict__ dst) {
    __shared__ __bf16 ax[2][32][40];
    __shared__ float hs[32][264];
    __shared__ float red[2][4][32];
    const int t = threadIdx.x;
    const int i0 = blockIdx.x * 32;
    const int l = t & 63, wv = t >> 6, ln = l & 15, g = l >> 4;
    f32x4 acc[2][4];
    #pragma unroll
    for (int mt = 0; mt < 2; ++mt)
        #pragma unroll
        for (int nt = 0; nt < 4; ++nt)
            acc[mt][nt] = (f32x4){0.f, 0.f, 0.f, 0.f};

    for (int ks = 0; ks < 8; ++ks) {
        const int k0 = ks * 32;
        {
            int row = t >> 3, c4 = (t & 7) * 4;
            float4 xv = *(const float4*)&X[(size_t)(i0 + row) * FF + k0 + c4];
            bf16x4 hi4, lo4;
            float xs_[4] = {xv.x, xv.y, xv.z, xv.w};
            #pragma unroll
            for (int u = 0; u < 4; ++u) {
                __bf16 h1 = (__bf16)xs_[u];
                hi4[u] = h1;
                lo4[u] = (__bf16)(xs_[u] - (float)h1);
            }
            *(bf16x4*)&ax[0][row][c4] = hi4;
            *(bf16x4*)&ax[1][row][c4] = lo4;
        }
        __syncthreads();
        bf16x8 ah[2], al[2];
        ah[0] = *(bf16x8*)&ax[0][ln][g * 8];
        ah[1] = *(bf16x8*)&ax[0][16 + ln][g * 8];
        al[0] = *(bf16x8*)&ax[1][ln][g * 8];
        al[1] = *(bf16x8*)&ax[1][16 + ln][g * 8];
        #pragma unroll
        for (int nt = 0; nt < 4; ++nt) {
            const int n = wv * 64 + nt * 16 + ln;
            bf16x8 bh8 = *(const bf16x8*)&WT[(size_t)n * FF + k0 + g * 8];
            bf16x8 bl8 = *(const bf16x8*)&WT[(size_t)(FF + n) * FF + k0 + g * 8];
            #pragma unroll
            for (int mt = 0; mt < 2; ++mt) {
                acc[mt][nt] = __builtin_amdgcn_mfma_f32_16x16x32_bf16(ah[mt], bh8, acc[mt][nt], 0, 0, 0);
                acc[mt][nt] = __builtin_amdgcn_mfma_f32_16x16x32_bf16(ah[mt], bl8, acc[mt][nt], 0, 0, 0);
                acc[mt][nt] = __builtin_amdgcn_mfma_f32_16x16x32_bf16(al[mt], bh8, acc[mt][nt], 0, 0, 0);
            }
        }
        __syncthreads();
    }
    float an[4], ad[4];
    #pragma unroll
    for (int nt = 0; nt < 4; ++nt) {
        an[nt] = a[wv * 64 + nt * 16 + ln];
        ad[nt] = a[FF + wv * 64 + nt * 16 + ln];
    }
    float sp[2][4], dp[2][4];
    #pragma unroll
    for (int mt = 0; mt < 2; ++mt)
        #pragma unroll
        for (int rg = 0; rg < 4; ++rg) { sp[mt][rg] = 0.f; dp[mt][rg] = 0.f; }
    #pragma unroll
    for (int mt = 0; mt < 2; ++mt)
        #pragma unroll
        for (int nt = 0; nt < 4; ++nt)
            #pragma unroll
            for (int rg = 0; rg < 4; ++rg) {
                float v = acc[mt][nt][rg];
                hs[mt * 16 + g * 4 + rg][wv * 64 + nt * 16 + ln] = v;
                sp[mt][rg] += v * an[nt];
                dp[mt][rg] += v * ad[nt];
            }
    #pragma unroll
    for (int mk = 1; mk < 16; mk <<= 1)
        #pragma unroll
        for (int mt = 0; mt < 2; ++mt)
            #pragma unroll
            for (int rg = 0; rg < 4; ++rg) {
                sp[mt][rg] += __shfl_xor(sp[mt][rg], mk);
                dp[mt][rg] += __shfl_xor(dp[mt][rg], mk);
            }
    if (ln == 0) {
        #pragma unroll
        for (int mt = 0; mt < 2; ++mt)
            #pragma unroll
            for (int rg = 0; rg < 4; ++rg) {
                red[0][wv][mt * 16 + g * 4 + rg] = sp[mt][rg];
                red[1][wv][mt * 16 + g * 4 + rg] = dp[mt][rg];
            }
    }
    __syncthreads();
    if (t < 32) {
        src[i0 + t] = red[0][0][t] + red[0][1][t] + red[0][2][t] + red[0][3][t];
        dst[i0 + t] = red[1][0][t] + red[1][1][t] + red[1][2][t] + red[1][3][t];
    }
    {
        const int f = t;
        #pragma unroll
        for (int jc = 0; jc < 4; ++jc) {
            union { bf16x8 v; __bf16 e[8]; } hi;
            #pragma unroll
            for (int u = 0; u < 8; ++u)
                hi.e[u] = (__bf16)hs[jc * 8 + u][f];
            *(bf16x8*)&hT[(size_t)f * NN + i0 + jc * 8] = hi.v;
        }
    }
}

// ---------------- K2b: maxd = max_j dst_j ---------------------------------
__global__ __launch_bounds__(256) void k2b_max(const float* __restrict__ dst,
                                               float* __restrict__ maxd) {
    __shared__ float red[256];
    float m = -1e30f;
    #pragma unroll
    for (int r = 0; r < NN / 1024; ++r) {
        float4 v = *(const float4*)&dst[(r * 256 + threadIdx.x) * 4];
        m = fmaxf(m, fmaxf(fmaxf(v.x, v.y), fmaxf(v.z, v.w)));
    }
    red[threadIdx.x] = m;
    __syncthreads();
    for (int s = 128; s > 0; s >>= 1) {
        if (threadIdx.x < s) red[threadIdx.x] = fmaxf(red[threadIdx.x], red[threadIdx.x + s]);
        __syncthreads();
    }
    if (threadIdx.x == 0) maxd[0] = red[0];
}

// ---------------- K3: 2-row-tile waves, B-reuse=2 MFMA pipeline -----------
// Wave wv: row-group rgp=wv>>1 (rows i0+rgp*32..+32, two 16-row A tiles),
// f-half fh=wv&1 (f in fh*128..+128, 8 B-chunks). Per step: 8 ds_read_b128
// feed 16 MFMAs (B-reuse=2, halves the LDS-read bound vs R9's 16).
// Ledger/half-step: pref(maskA,maskB,dst x2)=4 loads -> vmcnt(4) [retires
// DMA(s)x4] -> lgkmcnt(0) -> s_barrier -> DMA(s+1)x4 -> 8x ds_read + 16 MFMA.
__global__ __launch_bounds__(256, 3) void k3_attn(const unsigned int* __restrict__ mask,
                                                  const __bf16* __restrict__ hT,
                                                  const float* __restrict__ src,
                                                  const float* __restrict__ dst,
                                                  const float* __restrict__ maxd,
                                                  float* __restrict__ num,
                                                  float* __restrict__ den,
                                                  int jseg, int steps) {
    __shared__ __bf16 bh[2][1024 * 8];   // 2 x 16 KB
    const int t = threadIdx.x;
    const int l = t & 63, wv = t >> 6, ln = l & 15, g = l >> 4;
    const int rgp = wv >> 1, fh = wv & 1;
    const int it = blockIdx.x & 127;
    const int seg = blockIdx.x >> 7;
    const int i0 = it * 64;
    const int jbeg = seg * jseg;
    const int rowA = i0 + rgp * 32 + ln;
    const int rowB = rowA + 16;
    const float maxdv = maxd[0];
    const float srcA = src[rowA], srcB = src[rowB];
    const float eA0 = srcA + maxdv, eB0 = srcB + maxdv;
    const float mA_ = eA0 > 0.f ? eA0 : ALPHA * eA0;
    const float mB_ = eB0 > 0.f ? eB0 : ALPHA * eB0;

    // DMA staging descriptors (full 256f x 32j tile split across 4 waves)
    int ga[4], cb[4];
    #pragma unroll
    for (int r = 0; r < 4; ++r) {
        int cbase = r * 256 + wv * 64;
        int c = cbase + l;
        int f = c >> 2;
        int pc = c & 3;
        int jc = pc ^ ((f >> 1) & 3);
        ga[r] = f * NN + jc * 8;
        cb[r] = __builtin_amdgcn_readfirstlane(cbase);
    }
    const unsigned int* mrowA = mask + (size_t)rowA * (NN / 32) + (jbeg >> 5);
    const unsigned int* mrowB = mask + (size_t)rowB * (NN / 32) + (jbeg >> 5);
    const float* drow = dst + g * 8;

    // B-read base (bytes): f = fh*128 + nt*16 + ln ->
    // byte = fh*8192 + nt*1024 + ln*64 + (g^sw)*16, sw=((ln>>1)&3)
    const int rb = fh * 8192 + ln * 64 + ((g ^ ((ln >> 1) & 3)) * 16);
    const char* bh0 = (const char*)&bh[0][0] + rb;
    const char* bh1 = (const char*)&bh[1][0] + rb;

    // even/odd prefetch slots (scalars)
    unsigned int mAe, mBe, mAo, mBo;
    float4 d0e, d1e, d0o, d1o;

    // prologue: prefE(0)x4, DMA(0)x4, prefO(1)x4
    mAe = mrowA[0];
    mBe = mrowB[0];
    d0e = *(const float4*)(drow + jbeg);
    d1e = *(const float4*)(drow + jbeg + 4);
    FENCE;
    #pragma unroll
    for (int r = 0; r < 4; ++r)
        dma16(&hT[ga[r] + jbeg], &bh[0][cb[r] * 8]);
    FENCE;
    mAo = mrowA[1];
    mBo = mrowB[1];
    d0o = *(const float4*)(drow + jbeg + 32);
    d1o = *(const float4*)(drow + jbeg + 32 + 4);
    FENCE;

    float denA = 0.f, denB = 0.f;
    f32x4 accA[8], accB[8];
    #pragma unroll
    for (int nt = 0; nt < 8; ++nt) {
        accA[nt] = (f32x4){0.f, 0.f, 0.f, 0.f};
        accB[nt] = (f32x4){0.f, 0.f, 0.f, 0.f};
    }

#define K3_WCOMP(MA_, MB_, D0_, D1_, AFA_, AFB_)                              \
    {                                                                         \
        const unsigned int ba = ((MA_) >> (g * 8)) & 0xffu;                   \
        const unsigned int bb = ((MB_) >> (g * 8)) & 0xffu;                   \
        const float dv[8] = {D0_.x, D0_.y, D0_.z, D0_.w,                      \
                             D1_.x, D1_.y, D1_.z, D1_.w};                     \
        _Pragma("unroll")                                                     \
        for (int u = 0; u < 8; ++u) {                                         \
            float eA = srcA + dv[u];                                          \
            eA = eA > 0.f ? eA : ALPHA * eA;                                  \
            float wA = ((ba >> u) & 1u) ? __expf(eA - mA_) : 0.f;             \
            denA += wA;                                                       \
            AFA_[u] = (__bf16)wA;                                             \
            float eB = srcB + dv[u];                                          \
            eB = eB > 0.f ? eB : ALPHA * eB;                                  \
            float wB = ((bb >> u) & 1u) ? __expf(eB - mB_) : 0.f;             \
            denB += wB;                                                       \
            AFB_[u] = (__bf16)wB;                                             \
        }                                                                     \
    }

#define K3_PREF(MA_, MB_, D0_, D1_, SN_)                                      \
    MA_ = mrowA[SN_];                                                         \
    MB_ = mrowB[SN_];                                                         \
    D0_ = *(const float4*)(drow + jbeg + (SN_) * 32);                         \
    D1_ = *(const float4*)(drow + jbeg + (SN_) * 32 + 4);

#define K3_DMA(J1_, P_)                                                       \
    {                                                                         \
        _Pragma("unroll")                                                     \
        for (int r = 0; r < 4; ++r)                                           \
            dma16(&hT[ga[r] + (J1_)], &bh[P_][cb[r] * 8]);                    \
    }

#define K3_MFMA(AFA_, AFB_, BP_)                                              \
    {                                                                         \
        _Pragma("unroll")                                                     \
        for (int nt = 0; nt < 8; ++nt) {                                      \
            bf16x8 bfr = *(const bf16x8*)((BP_) + nt * 1024);                 \
            accA[nt] = __builtin_amdgcn_mfma_f32_16x16x32_bf16(               \
                AFA_, bfr, accA[nt], 0, 0, 0);                                \
            accB[nt] = __builtin_amdgcn_mfma_f32_16x16x32_bf16(               \
                AFB_, bfr, accB[nt], 0, 0, 0);                                \
        }                                                                     \
    }

    for (int su = 0; su < steps; su += 2) {
        // ---- even half: s = su, bh[0] ----
        bf16x8 afA, afB;
        K3_WCOMP(mAe, mBe, d0e, d1e, afA, afB);
        {
            const int sn = (su + 2 < steps) ? su + 2 : 0;
            K3_PREF(mAe, mBe, d0e, d1e, sn);
        }
        FENCE; VMCNT4; LGKM0; BARRIER;
        K3_DMA(jbeg + (su + 1) * 32, 1);
        FENCE;
        K3_MFMA(afA, afB, bh0);
        // ---- odd half: s = su+1, bh[1] ----
        bf16x8 afC, afD;
        K3_WCOMP(mAo, mBo, d0o, d1o, afC, afD);
        {
            const int sn = (su + 3 < steps) ? su + 3 : 0;
            K3_PREF(mAo, mBo, d0o, d1o, sn);
        }
        FENCE; VMCNT4; LGKM0; BARRIER;
        {
            const int s2 = (su + 2 < steps) ? su + 2 : 0;
            K3_DMA(jbeg + s2 * 32, 0);
        }
        FENCE;
        K3_MFMA(afC, afD, bh1);
    }
    // epilogue: den reduce over g (xor bits 4,5); fh==0 wave writes
    denA += __shfl_xor(denA, 16);
    denA += __shfl_xor(denA, 32);
    denB += __shfl_xor(denB, 16);
    denB += __shfl_xor(denB, 32);
    if (g == 0 && fh == 0) {
        den[(size_t)seg * NN + rowA] = denA;
        den[(size_t)seg * NN + rowB] = denB;
    }
    // num: C layout col=ln (within f-chunk), row m = g*4+rg
    #pragma unroll
    for (int nt = 0; nt < 8; ++nt)
        #pragma unroll
        for (int rg = 0; rg < 4; ++rg) {
            const int fcol = fh * 128 + nt * 16 + ln;
            num[((size_t)seg * NN + i0 + rgp * 32 + g * 4 + rg) * FF + fcol] = accA[nt][rg];
            num[((size_t)seg * NN + i0 + rgp * 32 + 16 + g * 4 + rg) * FF + fcol] = accB[nt][rg];
        }
}

// ---------------- K4: out = relu( sum_s num / sum_s den ) -----------------
__global__ __launch_bounds__(256) void k4_out(const float* __restrict__ num,
                                              const float* __restrict__ den,
                                              float* __restrict__ out, int S) {
    size_t f4 = (size_t)blockIdx.x * 256 + threadIdx.x;
    int i = (int)(f4 >> 6);
    int c4 = (int)(f4 & 63) << 2;
    float4 s = make_float4(0.f, 0.f, 0.f, 0.f);
    float d = 0.f;
    for (int sg = 0; sg < S; ++sg) {
        float4 v = *(const float4*)&num[((size_t)sg * NN + i) * FF + c4];
        s.x += v.x; s.y += v.y; s.z += v.z; s.w += v.w;
        d += den[(size_t)sg * NN + i];
    }
    float inv = 1.f / d;
    float4 o;
    o.x = fmaxf(s.x * inv, 0.f);
    o.y = fmaxf(s.y * inv, 0.f);
    o.z = fmaxf(s.z * inv, 0.f);
    o.w = fmaxf(s.w * inv, 0.f);
    *(float4*)&out[(size_t)i * FF + c4] = o;
}

extern "C" void kernel_launch(void* const* d_in, const int* in_sizes, int n_in,
                              void* d_out, int out_size, void* d_ws, size_t ws_size,
                              hipStream_t stream) {
    const float* X  = (const float*)d_in[0];
    const int*  adj = (const int*)d_in[1];
    const float* W  = (const float*)d_in[2];
    const float* a  = (const float*)d_in[3];
    float* out = (float*)d_out;
    char* ws = (char*)d_ws;

    const size_t off_hT   = 0;                                   // 4 MB
    const size_t off_mask = off_hT + (size_t)NN * FF * 2;        // 8 MB
    const size_t off_wt   = off_mask + (size_t)NN * (NN / 32) * 4;
    const size_t off_src  = off_wt + (size_t)2 * FF * FF * 2;
    const size_t off_dst  = off_src + (size_t)NN * 4;
    const size_t off_maxd = off_dst + (size_t)NN * 4;
    const size_t off_num  = off_maxd + 256;

    int SSv = 8;
    if (off_num + (size_t)8 * NN * FF * 4 + (size_t)8 * NN * 4 > ws_size) SSv = 4;
    const size_t off_den = off_num + (size_t)SSv * NN * FF * 4;
    const int jseg = NN / SSv;
    const int steps = jseg / 32;

    __bf16* hT_ws = (__bf16*)(ws + off_hT);
    unsigned int* mask_ws = (unsigned int*)(ws + off_mask);
    __bf16* wt_ws = (__bf16*)(ws + off_wt);
    float* src_ws = (float*)(ws + off_src);
    float* dst_ws = (float*)(ws + off_dst);
    float* maxd   = (float*)(ws + off_maxd);
    float* num_ws = (float*)(ws + off_num);
    float* den_ws = (float*)(ws + off_den);

    k5_pack<<<2048, 256, 0, stream>>>(adj, mask_ws);
    k0_wt<<<dim3(FF / 64, FF / 64), 256, 0, stream>>>(W, wt_ws);
    k1_h<<<NN / 32, 256, 0, stream>>>(X, wt_ws, a, hT_ws, src_ws, dst_ws);
    k2b_max<<<1, 256, 0, stream>>>(dst_ws, maxd);
    k3_attn<<<128 * SSv, 256, 0, stream>>>(mask_ws, hT_ws, src_ws, dst_ws, maxd,
                                           num_ws, den_ws, jseg, steps);
    k4_out<<<(NN * FF / 4) / 256, 256, 0, stream>>>(num_ws, den_ws, out, SSv);
}

// Round 11
// 469.241 us; speedup vs baseline: 1.0667x; 1.0667x over previous
//
#include <hip/hip_runtime.h>
#include <math.h>

#define NN 8192
#define FF 256
#define ALPHA 0.2f

typedef __bf16 bf16x8 __attribute__((ext_vector_type(8)));
typedef __bf16 bf16x4 __attribute__((ext_vector_type(4)));
typedef float  f32x4  __attribute__((ext_vector_type(4)));

__device__ __forceinline__ void dma16(const void* g, void* l) {
    __builtin_amdgcn_global_load_lds((const __attribute__((address_space(1))) void*)g,
                                     (__attribute__((address_space(3))) void*)l,
                                     16, 0, 0);
}

#define VMCNT3   asm volatile("s_waitcnt vmcnt(3)" ::: "memory")
#define LGKM0    asm volatile("s_waitcnt lgkmcnt(0)" ::: "memory")
#define BARRIER  asm volatile("s_barrier" ::: "memory")
#define FENCE    asm volatile("" ::: "memory")

// ---------------- K0: WT[hl][n][k] bf16 hi/lo from W[k][n] fp32 -----------
__global__ __launch_bounds__(256) void k0_wt(const float* __restrict__ W,
                                             __bf16* __restrict__ WT) {
    __shared__ float ts[64][65];
    const int t = threadIdx.x;
    const int k0 = blockIdx.x * 64;
    const int n0 = blockIdx.y * 64;
    #pragma unroll
    for (int r = 0; r < 4; ++r) {
        int krow = r * 16 + (t >> 4);
        int nc4 = (t & 15) * 4;
        *(float4*)&ts[krow][nc4] = *(const float4*)&W[(size_t)(k0 + krow) * FF + n0 + nc4];
    }
    __syncthreads();
    const int nloc = t >> 2;
    const int kc = (t & 3) * 16;
    union { bf16x8 v[2]; __bf16 e[16]; } hi, lo;
    #pragma unroll
    for (int u = 0; u < 16; ++u) {
        float x = ts[kc + u][nloc];
        __bf16 h1 = (__bf16)x;
        hi.e[u] = h1;
        lo.e[u] = (__bf16)(x - (float)h1);
    }
    size_t base = (size_t)(n0 + nloc) * FF + k0 + kc;
    *(bf16x8*)&WT[base] = hi.v[0];
    *(bf16x8*)&WT[base + 8] = hi.v[1];
    size_t lbase = (size_t)FF * FF + base;
    *(bf16x8*)&WT[lbase] = lo.v[0];
    *(bf16x8*)&WT[lbase + 8] = lo.v[1];
}

// ---------------- K5: bit-pack adj -> mask (8 MB) -------------------------
__global__ __launch_bounds__(256) void k5_pack(const int* __restrict__ adj,
                                               unsigned int* __restrict__ mask) {
    const int wv = threadIdx.x >> 6, l = threadIdx.x & 63;
    const size_t nwords = (size_t)NN * NN / 64;
    const size_t nw = (size_t)gridDim.x * 4;
    for (size_t w = (size_t)blockIdx.x * 4 + wv; w < nwords; w += nw) {
        int v = adj[w * 64 + l];
        unsigned long long b = __ballot(v > 0);
        if (l == 0) *(unsigned long long*)&mask[w * 2] = b;
    }
}

// ---------------- K1: MFMA h-tile -> hT (hi only, transposed) + src/dst ---
__global__ __launch_bounds__(256) void k1_h(const float* __restrict__ X,
                                            const __bf16* __restrict__ WT,
                                            const float* __restrict__ a,
                                            __bf16* __restrict__ hT,
                                            float* __restrict__ src,
                                            float* __restrict__ dst) {
    __shared__ __bf16 ax[2][32][40];
    __shared__ float hs[32][264];
    __shared__ float red[2][4][32];
    const int t = threadIdx.x;
    const int i0 = blockIdx.x * 32;
    const int l = t & 63, wv = t >> 6, ln = l & 15, g = l >> 4;
    f32x4 acc[2][4];
    #pragma unroll
    for (int mt = 0; mt < 2; ++mt)
        #pragma unroll
        for (int nt = 0; nt < 4; ++nt)
            acc[mt][nt] = (f32x4){0.f, 0.f, 0.f, 0.f};

    for (int ks = 0; ks < 8; ++ks) {
        const int k0 = ks * 32;
        {
            int row = t >> 3, c4 = (t & 7) * 4;
            float4 xv = *(const float4*)&X[(size_t)(i0 + row) * FF + k0 + c4];
            bf16x4 hi4, lo4;
            float xs_[4] = {xv.x, xv.y, xv.z, xv.w};
            #pragma unroll
            for (int u = 0; u < 4; ++u) {
                __bf16 h1 = (__bf16)xs_[u];
                hi4[u] = h1;
                lo4[u] = (__bf16)(xs_[u] - (float)h1);
            }
            *(bf16x4*)&ax[0][row][c4] = hi4;
            *(bf16x4*)&ax[1][row][c4] = lo4;
        }
        __syncthreads();
        bf16x8 ah[2], al[2];
        ah[0] = *(bf16x8*)&ax[0][ln][g * 8];
        ah[1] = *(bf16x8*)&ax[0][16 + ln][g * 8];
        al[0] = *(bf16x8*)&ax[1][ln][g * 8];
        al[1] = *(bf16x8*)&ax[1][16 + ln][g * 8];
        #pragma unroll
        for (int nt = 0; nt < 4; ++nt) {
            const int n = wv * 64 + nt * 16 + ln;
            bf16x8 bh8 = *(const bf16x8*)&WT[(size_t)n * FF + k0 + g * 8];
            bf16x8 bl8 = *(const bf16x8*)&WT[(size_t)(FF + n) * FF + k0 + g * 8];
            #pragma unroll
            for (int mt = 0; mt < 2; ++mt) {
                acc[mt][nt] = __builtin_amdgcn_mfma_f32_16x16x32_bf16(ah[mt], bh8, acc[mt][nt], 0, 0, 0);
                acc[mt][nt] = __builtin_amdgcn_mfma_f32_16x16x32_bf16(ah[mt], bl8, acc[mt][nt], 0, 0, 0);
                acc[mt][nt] = __builtin_amdgcn_mfma_f32_16x16x32_bf16(al[mt], bh8, acc[mt][nt], 0, 0, 0);
            }
        }
        __syncthreads();
    }
    float an[4], ad[4];
    #pragma unroll
    for (int nt = 0; nt < 4; ++nt) {
        an[nt] = a[wv * 64 + nt * 16 + ln];
        ad[nt] = a[FF + wv * 64 + nt * 16 + ln];
    }
    float sp[2][4], dp[2][4];
    #pragma unroll
    for (int mt = 0; mt < 2; ++mt)
        #pragma unroll
        for (int rg = 0; rg < 4; ++rg) { sp[mt][rg] = 0.f; dp[mt][rg] = 0.f; }
    #pragma unroll
    for (int mt = 0; mt < 2; ++mt)
        #pragma unroll
        for (int nt = 0; nt < 4; ++nt)
            #pragma unroll
            for (int rg = 0; rg < 4; ++rg) {
                float v = acc[mt][nt][rg];
                hs[mt * 16 + g * 4 + rg][wv * 64 + nt * 16 + ln] = v;
                sp[mt][rg] += v * an[nt];
                dp[mt][rg] += v * ad[nt];
            }
    #pragma unroll
    for (int mk = 1; mk < 16; mk <<= 1)
        #pragma unroll
        for (int mt = 0; mt < 2; ++mt)
            #pragma unroll
            for (int rg = 0; rg < 4; ++rg) {
                sp[mt][rg] += __shfl_xor(sp[mt][rg], mk);
                dp[mt][rg] += __shfl_xor(dp[mt][rg], mk);
            }
    if (ln == 0) {
        #pragma unroll
        for (int mt = 0; mt < 2; ++mt)
            #pragma unroll
            for (int rg = 0; rg < 4; ++rg) {
                red[0][wv][mt * 16 + g * 4 + rg] = sp[mt][rg];
                red[1][wv][mt * 16 + g * 4 + rg] = dp[mt][rg];
            }
    }
    __syncthreads();
    if (t < 32) {
        src[i0 + t] = red[0][0][t] + red[0][1][t] + red[0][2][t] + red[0][3][t];
        dst[i0 + t] = red[1][0][t] + red[1][1][t] + red[1][2][t] + red[1][3][t];
    }
    {
        const int f = t;
        #pragma unroll
        for (int jc = 0; jc < 4; ++jc) {
            union { bf16x8 v; __bf16 e[8]; } hi;
            #pragma unroll
            for (int u = 0; u < 8; ++u)
                hi.e[u] = (__bf16)hs[jc * 8 + u][f];
            *(bf16x8*)&hT[(size_t)f * NN + i0 + jc * 8] = hi.v;
        }
    }
}

// ---------------- K2b: maxd = max_j dst_j ---------------------------------
__global__ __launch_bounds__(256) void k2b_max(const float* __restrict__ dst,
                                               float* __restrict__ maxd) {
    __shared__ float red[256];
    float m = -1e30f;
    #pragma unroll
    for (int r = 0; r < NN / 1024; ++r) {
        float4 v = *(const float4*)&dst[(r * 256 + threadIdx.x) * 4];
        m = fmaxf(m, fmaxf(fmaxf(v.x, v.y), fmaxf(v.z, v.w)));
    }
    red[threadIdx.x] = m;
    __syncthreads();
    for (int s = 128; s > 0; s >>= 1) {
        if (threadIdx.x < s) red[threadIdx.x] = fmaxf(red[threadIdx.x], red[threadIdx.x + s]);
        __syncthreads();
    }
    if (threadIdx.x == 0) maxd[0] = red[0];
}

// ---------------- K3: w-share MFMA pipeline (B-reuse=2, exp once) ---------
// Wave (rgp=wv>>1, fh=wv&1): computes w ONCE for its own 16 rows
// (rgp*32+fh*16..+16), keeps own A-frag in regs, ds_writes it LANE-LINEAR
// (tile + lane*16B, conflict-free) to wsh, reads only the partner tile after
// the barrier. MFMA: 32 rows x 128-f half = 8 B-reads feeding 16 MFMAs.
// LDS ops/wave-step: 8 B + 1 write + 1 read = 10 (R9 was 16); exps 8 (R10
// doubled them — the regression). Ledger identical to R9 (3 pref + 4 DMA,
// vmcnt(3) retires prev pref x3 + DMA(s) x4).
__global__ __launch_bounds__(256, 4) void k3_attn(const unsigned int* __restrict__ mask,
                                                  const __bf16* __restrict__ hT,
                                                  const float* __restrict__ src,
                                                  const float* __restrict__ dst,
                                                  const float* __restrict__ maxd,
                                                  float* __restrict__ num,
                                                  float* __restrict__ den,
                                                  int jseg, int steps) {
    __shared__ __bf16 bh[2][1024 * 8];     // 2 x 16 KB B tiles
    __shared__ __bf16 wsh[2][2][2][512];   // [dbuf][rgp][fh][lane*8]  8 KB
    const int t = threadIdx.x;
    const int l = t & 63, wv = t >> 6, ln = l & 15, g = l >> 4;
    const int rgp = wv >> 1, fh = wv & 1;
    const int it = blockIdx.x & 127;
    const int seg = blockIdx.x >> 7;
    const int i0 = it * 64;
    const int jbeg = seg * jseg;
    const int rowO = i0 + rgp * 32 + fh * 16 + ln;   // own w row
    const float maxdv = maxd[0];
    const float src_r = src[rowO];
    const float e0 = src_r + maxdv;
    const float m_r = e0 > 0.f ? e0 : ALPHA * e0;

    // DMA staging descriptors (full 256f x 32j tile split across 4 waves)
    int ga[4], cb[4];
    #pragma unroll
    for (int r = 0; r < 4; ++r) {
        int cbase = r * 256 + wv * 64;
        int c = cbase + l;
        int f = c >> 2;
        int pc = c & 3;
        int jc = pc ^ ((f >> 1) & 3);
        ga[r] = f * NN + jc * 8;
        cb[r] = __builtin_amdgcn_readfirstlane(cbase);
    }
    const unsigned int* mrow = mask + (size_t)rowO * (NN / 32) + (jbeg >> 5);
    const float* drow = dst + g * 8;

    // B-read base (bytes): f = fh*128 + nt*16 + ln ->
    // byte = fh*8192 + nt*1024 + ln*64 + (g^sw)*16, sw=((ln>>1)&3)
    const int rb = fh * 8192 + ln * 64 + ((g ^ ((ln >> 1) & 3)) * 16);
    const char* bh0 = (const char*)&bh[0][0] + rb;
    const char* bh1 = (const char*)&bh[1][0] + rb;
    // w-share: own tile write ptr / partner tile read ptr (lane-linear)
    __bf16* wshW0 = &wsh[0][rgp][fh][l * 8];
    __bf16* wshW1 = &wsh[1][rgp][fh][l * 8];
    const __bf16* wshR0 = &wsh[0][rgp][fh ^ 1][l * 8];
    const __bf16* wshR1 = &wsh[1][rgp][fh ^ 1][l * 8];

    // even/odd prefetch slots (scalars)
    unsigned int mE, mO;
    float4 d0e, d1e, d0o, d1o;

    // prologue: prefE(0)x3, DMA(0)x4, prefO(1)x3
    mE = mrow[0];
    d0e = *(const float4*)(drow + jbeg);
    d1e = *(const float4*)(drow + jbeg + 4);
    FENCE;
    #pragma unroll
    for (int r = 0; r < 4; ++r)
        dma16(&hT[ga[r] + jbeg], &bh[0][cb[r] * 8]);
    FENCE;
    mO = mrow[1];
    d0o = *(const float4*)(drow + jbeg + 32);
    d1o = *(const float4*)(drow + jbeg + 32 + 4);
    FENCE;

    float den_reg = 0.f;
    f32x4 accO[8], accP[8];
    #pragma unroll
    for (int nt = 0; nt < 8; ++nt) {
        accO[nt] = (f32x4){0.f, 0.f, 0.f, 0.f};
        accP[nt] = (f32x4){0.f, 0.f, 0.f, 0.f};
    }

#define K3_WCOMP(M_, D0_, D1_, AF_)                                           \
    {                                                                         \
        const unsigned int bits = ((M_) >> (g * 8)) & 0xffu;                  \
        const float dv[8] = {D0_.x, D0_.y, D0_.z, D0_.w,                      \
                             D1_.x, D1_.y, D1_.z, D1_.w};                     \
        _Pragma("unroll")                                                     \
        for (int u = 0; u < 8; ++u) {                                         \
            float e = src_r + dv[u];                                          \
            e = e > 0.f ? e : ALPHA * e;                                      \
            float w = ((bits >> u) & 1u) ? __expf(e - m_r) : 0.f;             \
            den_reg += w;                                                     \
            AF_[u] = (__bf16)w;                                               \
        }                                                                     \
    }

#define K3_PREF(M_, D0_, D1_, SN_)                                            \
    M_ = mrow[SN_];                                                           \
    D0_ = *(const float4*)(drow + jbeg + (SN_) * 32);                         \
    D1_ = *(const float4*)(drow + jbeg + (SN_) * 32 + 4);

#define K3_DMA(J1_, P_)                                                       \
    {                                                                         \
        _Pragma("unroll")                                                     \
        for (int r = 0; r < 4; ++r)                                           \
            dma16(&hT[ga[r] + (J1_)], &bh[P_][cb[r] * 8]);                    \
    }

#define K3_MFMA(AFO_, AFP_, BP_)                                              \
    {                                                                         \
        _Pragma("unroll")                                                     \
        for (int nt = 0; nt < 8; ++nt) {                                      \
            bf16x8 bfr = *(const bf16x8*)((BP_) + nt * 1024);                 \
            accO[nt] = __builtin_amdgcn_mfma_f32_16x16x32_bf16(               \
                AFO_, bfr, accO[nt], 0, 0, 0);                                \
            accP[nt] = __builtin_amdgcn_mfma_f32_16x16x32_bf16(               \
                AFP_, bfr, accP[nt], 0, 0, 0);                                \
        }                                                                     \
    }

    for (int su = 0; su < steps; su += 2) {
        // ---- even half: s = su, bh[0], wsh[0] ----
        {
            bf16x8 afO;
            K3_WCOMP(mE, d0e, d1e, afO);
            *(bf16x8*)wshW0 = afO;                  // own tile -> LDS
            {
                const int sn = (su + 2 < steps) ? su + 2 : 0;
                K3_PREF(mE, d0e, d1e, sn);
            }
            FENCE; VMCNT3; LGKM0; BARRIER;
            K3_DMA(jbeg + (su + 1) * 32, 1);
            FENCE;
            bf16x8 afP = *(const bf16x8*)wshR0;     // partner tile
            K3_MFMA(afO, afP, bh0);
        }
        // ---- odd half: s = su+1, bh[1], wsh[1] ----
        {
            bf16x8 afO;
            K3_WCOMP(mO, d0o, d1o, afO);
            *(bf16x8*)wshW1 = afO;
            {
                const int sn = (su + 3 < steps) ? su + 3 : 0;
                K3_PREF(mO, d0o, d1o, sn);
            }
            FENCE; VMCNT3; LGKM0; BARRIER;
            {
                const int s2 = (su + 2 < steps) ? su + 2 : 0;
                K3_DMA(jbeg + s2 * 32, 0);
            }
            FENCE;
            bf16x8 afP = *(const bf16x8*)wshR1;
            K3_MFMA(afO, afP, bh1);
        }
    }
    // epilogue: den (own rows), reduce over g (xor bits 4,5)
    den_reg += __shfl_xor(den_reg, 16);
    den_reg += __shfl_xor(den_reg, 32);
    if (g == 0) den[(size_t)seg * NN + rowO] = den_reg;
    // num: accO rows = rgp*32 + fh*16 + g*4+rg; accP rows = rgp*32 + (fh^1)*16
    #pragma unroll
    for (int nt = 0; nt < 8; ++nt)
        #pragma unroll
        for (int rg = 0; rg < 4; ++rg) {
            const int fcol = fh * 128 + nt * 16 + ln;
            num[((size_t)seg * NN + i0 + rgp * 32 + fh * 16 + g * 4 + rg) * FF + fcol] = accO[nt][rg];
            num[((size_t)seg * NN + i0 + rgp * 32 + (fh ^ 1) * 16 + g * 4 + rg) * FF + fcol] = accP[nt][rg];
        }
}

// ---------------- K4: out = relu( sum_s num / sum_s den ) -----------------
__global__ __launch_bounds__(256) void k4_out(const float* __restrict__ num,
                                              const float* __restrict__ den,
                                              float* __restrict__ out, int S) {
    size_t f4 = (size_t)blockIdx.x * 256 + threadIdx.x;
    int i = (int)(f4 >> 6);
    int c4 = (int)(f4 & 63) << 2;
    float4 s = make_float4(0.f, 0.f, 0.f, 0.f);
    float d = 0.f;
    for (int sg = 0; sg < S; ++sg) {
        float4 v = *(const float4*)&num[((size_t)sg * NN + i) * FF + c4];
        s.x += v.x; s.y += v.y; s.z += v.z; s.w += v.w;
        d += den[(size_t)sg * NN + i];
    }
    float inv = 1.f / d;
    float4 o;
    o.x = fmaxf(s.x * inv, 0.f);
    o.y = fmaxf(s.y * inv, 0.f);
    o.z = fmaxf(s.z * inv, 0.f);
    o.w = fmaxf(s.w * inv, 0.f);
    *(float4*)&out[(size_t)i * FF + c4] = o;
}

extern "C" void kernel_launch(void* const* d_in, const int* in_sizes, int n_in,
                              void* d_out, int out_size, void* d_ws, size_t ws_size,
                              hipStream_t stream) {
    const float* X  = (const float*)d_in[0];
    const int*  adj = (const int*)d_in[1];
    const float* W  = (const float*)d_in[2];
    const float* a  = (const float*)d_in[3];
    float* out = (float*)d_out;
    char* ws = (char*)d_ws;

    const size_t off_hT   = 0;                                   // 4 MB
    const size_t off_mask = off_hT + (size_t)NN * FF * 2;        // 8 MB
    const size_t off_wt   = off_mask + (size_t)NN * (NN / 32) * 4;
    const size_t off_src  = off_wt + (size_t)2 * FF * FF * 2;
    const size_t off_dst  = off_src + (size_t)NN * 4;
    const size_t off_maxd = off_dst + (size_t)NN * 4;
    const size_t off_num  = off_maxd + 256;

    int SSv = 8;
    if (off_num + (size_t)8 * NN * FF * 4 + (size_t)8 * NN * 4 > ws_size) SSv = 4;
    const size_t off_den = off_num + (size_t)SSv * NN * FF * 4;
    const int jseg = NN / SSv;
    const int steps = jseg / 32;

    __bf16* hT_ws = (__bf16*)(ws + off_hT);
    unsigned int* mask_ws = (unsigned int*)(ws + off_mask);
    __bf16* wt_ws = (__bf16*)(ws + off_wt);
    float* src_ws = (float*)(ws + off_src);
    float* dst_ws = (float*)(ws + off_dst);
    float* maxd   = (float*)(ws + off_maxd);
    float* num_ws = (float*)(ws + off_num);
    float* den_ws = (float*)(ws + off_den);

    k5_pack<<<2048, 256, 0, stream>>>(adj, mask_ws);
    k0_wt<<<dim3(FF / 64, FF / 64), 256, 0, stream>>>(W, wt_ws);
    k1_h<<<NN / 32, 256, 0, stream>>>(X, wt_ws, a, hT_ws, src_ws, dst_ws);
    k2b_max<<<1, 256, 0, stream>>>(dst_ws, maxd);
    k3_attn<<<128 * SSv, 256, 0, stream>>>(mask_ws, hT_ws, src_ws, dst_ws, maxd,
                                           num_ws, den_ws, jseg, steps);
    k4_out<<<(NN * FF / 4) / 256, 256, 0, stream>>>(num_ws, den_ws, out, SSv);
}